// Round 10
// baseline (59356.067 us; speedup 1.0000x reference)
//
#include <hip/hip_runtime.h>
#include <stdint.h>
#include <math.h>

// ---------------------------------------------------------------------------
// Round 10: single-barrier phase pipeline + pinned register budget.
//  * __attribute__((amdgpu_waves_per_eu(2,2))): min=max pins the allocator at
//    512/2=256 unified regs -> no occupancy-chasing clamp to 128, no spills
//    (R5/R8/R9 all showed the clamp: VGPR_Count=128 + 1.7-2.9 GB scratch).
//  * Algebraic restructure: mu_t = h_{t+1}.w_mu is next phase's h.w_mu, and
//    z/logw are state-independent. Phase t computes gates AND mu/ls from the
//    same h_t (mu redundantly per rt across cg waves -> bitwise identical),
//    z via one threefry per lane at phase top (off critical path).
//    => ONE barrier/step, no serial wave-0 RNG, no cross-wave x traffic.
//  * x*W_ih + b folded post-MFMA (x unknown at C-init).
// ---------------------------------------------------------------------------

#define HH     128
#define NG     512
#define NB     8192
#define NSAMP  100
#define NSTEP  20
#define NHIST  126
#define NRET   127

using bfrag = __attribute__((ext_vector_type(8))) short;   // 8 bf16 = 4 VGPRs
using facc  = __attribute__((ext_vector_type(16))) float;  // 16 f32 acc

// LDS frag strides (shorts): per-(kb,hs) region 264 (8 pad), per-kb 528.
#define SHS 264
#define SKB 528
#define HFN 4224   // 8 kb * 528

// ----------------------------- threefry2x32 --------------------------------
__device__ __forceinline__ void tf2x32(uint32_t k0, uint32_t k1,
                                       uint32_t x0, uint32_t x1,
                                       uint32_t &y0, uint32_t &y1) {
  uint32_t ks2 = k0 ^ k1 ^ 0x1BD11BDAu;
  x0 += k0; x1 += k1;
#define RR(r) { x0 += x1; x1 = (x1 << (r)) | (x1 >> (32 - (r))); x1 ^= x0; }
  RR(13) RR(15) RR(26) RR(6)   x0 += k1;  x1 += ks2 + 1u;
  RR(17) RR(29) RR(16) RR(24)  x0 += ks2; x1 += k0  + 2u;
  RR(13) RR(15) RR(26) RR(6)   x0 += k0;  x1 += k1  + 3u;
  RR(17) RR(29) RR(16) RR(24)  x0 += k1;  x1 += ks2 + 4u;
  RR(13) RR(15) RR(26) RR(6)   x0 += ks2; x1 += k0  + 5u;
#undef RR
  y0 = x0; y1 = x1;
}

__device__ __forceinline__ float erfinv32(float x) {
  float w = -__logf(fmaxf(1.0f - x * x, 1e-37f));
  float p;
  if (w < 5.0f) {
    w = w - 2.5f;
    p = 2.81022636e-08f;
    p = fmaf(p, w, 3.43273939e-07f);
    p = fmaf(p, w, -3.5233877e-06f);
    p = fmaf(p, w, -4.39150654e-06f);
    p = fmaf(p, w, 0.00021858087f);
    p = fmaf(p, w, -0.00125372503f);
    p = fmaf(p, w, -0.00417768164f);
    p = fmaf(p, w, 0.246640727f);
    p = fmaf(p, w, 1.50140941f);
  } else {
    w = sqrtf(w) - 3.0f;
    p = -0.000200214257f;
    p = fmaf(p, w, 0.000100950558f);
    p = fmaf(p, w, 0.00134934322f);
    p = fmaf(p, w, -0.00367342844f);
    p = fmaf(p, w, 0.00573950773f);
    p = fmaf(p, w, -0.0076224613f);
    p = fmaf(p, w, 0.00943887047f);
    p = fmaf(p, w, 1.00167406f);
    p = fmaf(p, w, 2.83297682f);
  }
  return p * x;
}

__device__ __forceinline__ float normal32(uint32_t k0, uint32_t k1, uint32_t idx) {
  uint32_t y0, y1;
  tf2x32(k0, k1, 0u, idx, y0, y1);
  uint32_t bits = y0 ^ y1;
  float f = __uint_as_float((bits >> 9) | 0x3f800000u) - 1.0f;
  const float lo = __uint_as_float(0xBF7FFFFFu);
  float u = fmaxf(lo, f * 2.0f + lo);
  return 1.41421356f * erfinv32(u);
}

__device__ __forceinline__ float fast_sigmoid(float x) {
  return __builtin_amdgcn_rcpf(1.0f + __expf(-x));
}
__device__ __forceinline__ float fast_tanh(float x) {
  return 1.0f - 2.0f * __builtin_amdgcn_rcpf(1.0f + __expf(2.0f * x));
}

__device__ __forceinline__ unsigned short f2bf(float x) {
  uint32_t u = __float_as_uint(x);
  uint32_t r = u + 0x7fffu + ((u >> 16) & 1u);
  return (unsigned short)(r >> 16);
}
__device__ __forceinline__ float bf2f(unsigned short h) {
  return __uint_as_float(((uint32_t)h) << 16);
}

// ------------------------------- small kernels -----------------------------
__global__ void returns_kernel(const float* __restrict__ inp,
                               const float* __restrict__ pert,
                               float* __restrict__ ret) {
  int i = blockIdx.x * blockDim.x + threadIdx.x;
  if (i >= NRET * NB) return;
  int s = i / NB, b = i - s * NB;
  float p0 = inp[s * NB + b] * (1.0f + pert[s * NB + b]);
  float p1 = inp[(s + 1) * NB + b] * (1.0f + pert[(s + 1) * NB + b]);
  ret[i] = p1 - p0;
}

__global__ void keys_kernel(uint32_t* __restrict__ keys) {
  int id = blockIdx.x * blockDim.x + threadIdx.x;
  if (id >= NSAMP * NSTEP) return;
  int s = id / NSTEP, t = id - s * NSTEP;
  uint32_t sk0, sk1, k0, k1;
  tf2x32(0u, 42u, 0u, (uint32_t)s, sk0, sk1);
  tf2x32(sk0, sk1, 0u, (uint32_t)t, k0, k1);
  keys[2 * id] = k0; keys[2 * id + 1] = k1;
}

// B-fragment pack: Bhi/Blo[((gct*8+kb)*64+lane)*8+j]
//   k = kb*16 + 8*(lane>>5) + j, g = 32*gct + (lane&31).
__global__ void pack_kernel(const float* __restrict__ W_hh,
                            const float* __restrict__ w_mu,
                            const float* __restrict__ w_ls,
                            unsigned short* __restrict__ Bhi,
                            unsigned short* __restrict__ Blo,
                            unsigned short* __restrict__ Bmu) {
  int idx = blockIdx.x * blockDim.x + threadIdx.x;
  if (idx < 65536) {
    int j = idx & 7, lane = (idx >> 3) & 63, kb = (idx >> 9) & 7, gct = idx >> 12;
    int k = kb * 16 + ((lane >> 5) << 3) + j;
    int g = (gct << 5) + (lane & 31);
    float w = W_hh[k * NG + g];
    unsigned short hi = f2bf(w);
    unsigned short lo = f2bf(w - bf2f(hi));
    Bhi[idx] = hi; Blo[idx] = lo;
  } else if (idx < 65536 + 4096) {
    int i2 = idx - 65536;
    int j = i2 & 7, lane = (i2 >> 3) & 63, kb = (i2 >> 9) & 7;
    int k = kb * 16 + ((lane >> 5) << 3) + j;
    int col = lane & 31;
    float v = (col == 0) ? w_mu[k] : (col == 1 ? w_ls[k] : 0.0f);
    Bmu[i2] = f2bf(v);
  }
}

// ------------------------------ history kernel -----------------------------
// 256 thr = 4 waves; wave cg owns 32 hidden cols x 4 gates, 32 rows/block.
__launch_bounds__(256, 1)
__global__ void hist_kernel(const float* __restrict__ ret,
                            const float* __restrict__ W_ih,
                            const float* __restrict__ bias,
                            const unsigned short* __restrict__ Bhi,
                            const unsigned short* __restrict__ Blo,
                            float* __restrict__ hout,
                            float* __restrict__ cout) {
  __shared__ unsigned short hfh[2][HFN];
  __shared__ unsigned short hfl[2][HFN];

  const int tid  = threadIdx.x;
  const int lane = tid & 63;
  const int cg   = tid >> 6;
  const int hs   = lane >> 5;
  const int m    = lane & 31;
  const int col  = (cg << 5) + m;
  const int b0   = blockIdx.x << 5;

  float wih_r[4], bb_r[4];
#pragma unroll
  for (int gi = 0; gi < 4; ++gi) {
    wih_r[gi] = W_ih[(gi << 7) + col];
    bb_r[gi]  = bias[(gi << 7) + col];
  }

  const int coff = (col >> 4) * SKB + ((col >> 3) & 1) * SHS + (col & 7);
  const int aoff = hs * SHS + m * 8;

  float c_reg[16];
#pragma unroll
  for (int reg = 0; reg < 16; ++reg) {
    int row32 = (reg & 3) + ((reg >> 2) << 3) + (hs << 2);
    c_reg[reg] = 0.0f;
    hfh[0][coff + row32 * 8] = 0;
    hfl[0][coff + row32 * 8] = 0;
  }
  __syncthreads();

  int buf = 0;
#pragma unroll 1
  for (int t = 0; t < NHIST; ++t) {
    const int nbuf = buf ^ 1;
    facc acc[4];
#pragma unroll
    for (int reg = 0; reg < 16; ++reg) {
      int row32 = (reg & 3) + ((reg >> 2) << 3) + (hs << 2);
      float xv = ret[t * NB + b0 + row32];
#pragma unroll
      for (int gi = 0; gi < 4; ++gi)
        acc[gi][reg] = fmaf(xv, wih_r[gi], bb_r[gi]);
    }
#pragma unroll 1
    for (int kb = 0; kb < 8; ++kb) {
      bfrag ah = *(const bfrag*)&hfh[buf][kb * SKB + aoff];
      bfrag al = *(const bfrag*)&hfl[buf][kb * SKB + aoff];
      bfrag bh[4], bl[4];
#pragma unroll
      for (int gi = 0; gi < 4; ++gi) {
        const int off = ((((gi << 2) + cg) << 3) + kb) * 512 + lane * 8;
        bh[gi] = *(const bfrag*)&Bhi[off];
        bl[gi] = *(const bfrag*)&Blo[off];
      }
#pragma unroll
      for (int gi = 0; gi < 4; ++gi)
        acc[gi] = __builtin_amdgcn_mfma_f32_32x32x16_bf16(ah, bh[gi], acc[gi], 0, 0, 0);
#pragma unroll
      for (int gi = 0; gi < 4; ++gi)
        acc[gi] = __builtin_amdgcn_mfma_f32_32x32x16_bf16(al, bh[gi], acc[gi], 0, 0, 0);
#pragma unroll
      for (int gi = 0; gi < 4; ++gi)
        acc[gi] = __builtin_amdgcn_mfma_f32_32x32x16_bf16(ah, bl[gi], acc[gi], 0, 0, 0);
    }
#pragma unroll
    for (int reg = 0; reg < 16; ++reg) {
      int row32 = (reg & 3) + ((reg >> 2) << 3) + (hs << 2);
      float ig = fast_sigmoid(acc[0][reg]);
      float fg = fast_sigmoid(acc[1][reg]);
      float gg = fast_tanh  (acc[2][reg]);
      float og = fast_sigmoid(acc[3][reg]);
      float c  = fmaf(fg, c_reg[reg], ig * gg);
      c_reg[reg] = c;
      float h  = og * fast_tanh(c);
      unsigned short hi = f2bf(h);
      unsigned short lo = f2bf(h - bf2f(hi));
      hfh[nbuf][coff + row32 * 8] = hi;
      hfl[nbuf][coff + row32 * 8] = lo;
      if (t == NHIST - 1) {
        hout[(b0 + row32) * HH + col] = h;
        cout[(b0 + row32) * HH + col] = c;
      }
    }
    __syncthreads();
    buf = nbuf;
  }
}

// -------------------------------- MC kernel --------------------------------
// 512 thr = 8 waves; wave w: cg=w>>1 (32 hidden cols x 4 gates), rt=w&1
// (32-row tile). Phase t: gates = h_t x W_hh AND mu/ls = h_t x Bmu (own rt,
// redundant across cg -> bitwise identical) + in-wave z; then x_t, gate-add,
// activations, h-frag write, ONE barrier.
__global__ __launch_bounds__(512)
__attribute__((amdgpu_waves_per_eu(2, 2)))
void mc_kernel(const float* __restrict__ ret,
               const float* __restrict__ W_ih,
               const float* __restrict__ bias,
               const unsigned short* __restrict__ Bhi,
               const unsigned short* __restrict__ Blo,
               const unsigned short* __restrict__ Bmu,
               const float* __restrict__ hin,
               const float* __restrict__ cin,
               const float* __restrict__ b_mu,
               const float* __restrict__ b_ls,
               const uint32_t* __restrict__ keys,
               float* __restrict__ accum) {
  __shared__ unsigned short hfh[2][2][HFN];
  __shared__ unsigned short hfl[2][2][HFN];
  __shared__ float sc[8][2][32];     // per-wave mu/ls broadcast
  __shared__ float zrow[8][2][32];   // per-wave z broadcast, phase parity
  __shared__ float x0s[64];
  __shared__ float xcap[64];
  __shared__ float lwcap[64];

  const int tid  = threadIdx.x;
  const int lane = tid & 63;
  const int w    = tid >> 6;
  const int cg   = w >> 1;
  const int rt   = w & 1;
  const int hs   = lane >> 5;
  const int m    = lane & 31;
  const int col  = (cg << 5) + m;

  const int s  = blockIdx.x >> 7;
  const int b0 = (blockIdx.x & 127) << 6;

  float wih_r[4], bb_r[4];
#pragma unroll
  for (int gi = 0; gi < 4; ++gi) {
    wih_r[gi] = W_ih[(gi << 7) + col];
    bb_r[gi]  = bias[(gi << 7) + col];
  }
  const float bmu = b_mu[0], bls = b_ls[0];

  const int coff = (col >> 4) * SKB + ((col >> 3) & 1) * SHS + (col & 7);
  const int aoff = hs * SHS + m * 8;

  // Bmu frags preloaded (8 x 4 regs)
  bfrag bmu_f[8];
#pragma unroll
  for (int kb = 0; kb < 8; ++kb)
    bmu_f[kb] = *(const bfrag*)&Bmu[kb * 512 + lane * 8];

  // init h frags (buf 0) + c regs (this wave's rt tile, its col range)
  float c_reg[16];
#pragma unroll
  for (int reg = 0; reg < 16; ++reg) {
    int row32 = (reg & 3) + ((reg >> 2) << 3) + (hs << 2);
    int grow = b0 + (rt << 5) + row32;
    float hv = hin[grow * HH + col];
    c_reg[reg] = cin[grow * HH + col];
    unsigned short hi = f2bf(hv);
    unsigned short lo = f2bf(hv - bf2f(hi));
    hfh[0][rt][coff + row32 * 8] = hi;
    hfl[0][rt][coff + row32 * 8] = lo;
  }
  if (tid < 64) x0s[tid] = ret[126 * NB + b0 + tid];
  float logw = 0.0f;
  __syncthreads();

  int buf = 0;
#pragma unroll 1
  for (int t = 0; t < NSTEP; ++t) {
    const int nbuf = buf ^ 1;
    const int par = t & 1;

    // z_t for this wave's rows (independent of state; off critical path)
    {
      uint32_t k0 = keys[2 * (s * NSTEP + t)];
      uint32_t k1 = keys[2 * (s * NSTEP + t) + 1];
      float z = normal32(k0, k1, (uint32_t)(b0 + (rt << 5) + m));
      logw -= fmaf(0.5f, z, 0.125f);
      if (hs == 0) zrow[w][par][m] = z;
    }

    // gate + mu matmul from h_t (buf)
    facc acc[4];
#pragma unroll
    for (int gi = 0; gi < 4; ++gi)
#pragma unroll
      for (int e = 0; e < 16; ++e) acc[gi][e] = 0.0f;
    facc am;
#pragma unroll
    for (int e = 0; e < 16; ++e) am[e] = 0.0f;

#pragma unroll 1
    for (int kb = 0; kb < 8; ++kb) {
      bfrag ah = *(const bfrag*)&hfh[buf][rt][kb * SKB + aoff];
      bfrag al = *(const bfrag*)&hfl[buf][rt][kb * SKB + aoff];
      bfrag bh[4], bl[4];
#pragma unroll
      for (int gi = 0; gi < 4; ++gi) {
        const int off = ((((gi << 2) + cg) << 3) + kb) * 512 + lane * 8;
        bh[gi] = *(const bfrag*)&Bhi[off];
        bl[gi] = *(const bfrag*)&Blo[off];
      }
#pragma unroll
      for (int gi = 0; gi < 4; ++gi)
        acc[gi] = __builtin_amdgcn_mfma_f32_32x32x16_bf16(ah, bh[gi], acc[gi], 0, 0, 0);
      am = __builtin_amdgcn_mfma_f32_32x32x16_bf16(ah, bmu_f[kb], am, 0, 0, 0);
#pragma unroll
      for (int gi = 0; gi < 4; ++gi)
        acc[gi] = __builtin_amdgcn_mfma_f32_32x32x16_bf16(al, bh[gi], acc[gi], 0, 0, 0);
#pragma unroll
      for (int gi = 0; gi < 4; ++gi)
        acc[gi] = __builtin_amdgcn_mfma_f32_32x32x16_bf16(ah, bl[gi], acc[gi], 0, 0, 0);
    }

    // publish mu/ls (cols 0/1 of am) to per-wave scratch
    if (m < 2) {
#pragma unroll
      for (int reg = 0; reg < 16; ++reg) {
        int row32 = (reg & 3) + ((reg >> 2) << 3) + (hs << 2);
        sc[w][m][row32] = am[reg];
      }
    }
    // same-wave LDS RAW: compiler inserts lgkmcnt waits

    // x_t + gate-add + activations + h-frag write
#pragma unroll
    for (int reg = 0; reg < 16; ++reg) {
      int row32 = (reg & 3) + ((reg >> 2) << 3) + (hs << 2);
      float xv;
      if (t == 0) {
        xv = x0s[(rt << 5) + row32];
      } else {
        float mu = sc[w][0][row32] + bmu;
        float ls = fminf(fmaxf(sc[w][1][row32] + bls, -5.0f), 2.0f);
        float sg = __expf(ls);
        xv = fmaf(sg, zrow[w][par ^ 1][row32] + 0.5f, mu);
      }
      if (t == NSTEP - 1 && cg == 0 && m == 0) xcap[(rt << 5) + row32] = xv;
      float ig = fast_sigmoid(acc[0][reg] + fmaf(xv, wih_r[0], bb_r[0]));
      float fg = fast_sigmoid(acc[1][reg] + fmaf(xv, wih_r[1], bb_r[1]));
      float gg = fast_tanh  (acc[2][reg] + fmaf(xv, wih_r[2], bb_r[2]));
      float og = fast_sigmoid(acc[3][reg] + fmaf(xv, wih_r[3], bb_r[3]));
      float c  = fmaf(fg, c_reg[reg], ig * gg);
      c_reg[reg] = c;
      float h  = og * fast_tanh(c);
      unsigned short hi = f2bf(h);
      unsigned short lo = f2bf(h - bf2f(hi));
      hfh[nbuf][rt][coff + row32 * 8] = hi;
      hfl[nbuf][rt][coff + row32 * 8] = lo;
    }
    if (t == NSTEP - 1 && cg == 0 && hs == 0) lwcap[(rt << 5) + m] = logw;
    __syncthreads();   // ONE barrier: nbuf frags + (last phase) caps visible
    buf = nbuf;
  }

  if (tid < 64) {
    float out = xcap[lane];
    float wt  = __expf(lwcap[lane]);
    float ow  = out * wt;
    int b = b0 + lane;
    atomicAdd(&accum[0 * NB + b], wt);
    atomicAdd(&accum[1 * NB + b], ow);
    atomicAdd(&accum[2 * NB + b], wt * wt);
    atomicAdd(&accum[3 * NB + b], ow * ow);
    atomicAdd(&accum[4 * NB + b], out * wt * wt);
  }
}

// ------------------------------- final kernel ------------------------------
__global__ void final_kernel(const float* __restrict__ accum,
                             float* __restrict__ out) {
  int b = blockIdx.x * blockDim.x + threadIdx.x;
  if (b >= NB) return;
  float sw  = accum[0 * NB + b];
  float sm1 = accum[1 * NB + b];
  float sqw = accum[2 * NB + b];
  float sm2 = accum[3 * NB + b];
  float shm = accum[4 * NB + b];
  float mean = sm1 / sw;
  float sem = sm2 + sqw * mean * mean - 2.0f * shm * mean;
  sem = sqrtf(sem / (float)(NSAMP * (NSAMP - 1)));
  out[b] = mean;
  out[NB + b] = sem;
}

// ------------------------------- launcher ----------------------------------
extern "C" void kernel_launch(void* const* d_in, const int* in_sizes, int n_in,
                              void* d_out, int out_size, void* d_ws, size_t ws_size,
                              hipStream_t stream) {
  (void)in_sizes; (void)n_in; (void)out_size; (void)ws_size;
  const float* inp  = (const float*)d_in[0];
  const float* pert = (const float*)d_in[1];
  const float* W_ih = (const float*)d_in[2];
  const float* W_hh = (const float*)d_in[3];
  const float* bias = (const float*)d_in[4];
  const float* w_mu = (const float*)d_in[5];
  const float* b_mu = (const float*)d_in[6];
  const float* w_ls = (const float*)d_in[7];
  const float* b_ls = (const float*)d_in[8];

  char* ws = (char*)d_ws;
  float* ret = (float*)ws;        ws += (size_t)NRET * NB * sizeof(float);
  float* hh  = (float*)ws;        ws += (size_t)NB * HH * sizeof(float);
  float* cc  = (float*)ws;        ws += (size_t)NB * HH * sizeof(float);
  uint32_t* keys = (uint32_t*)ws; ws += (size_t)NSAMP * NSTEP * 2 * sizeof(uint32_t);
  float* accum = (float*)ws;      ws += (size_t)5 * NB * sizeof(float);
  unsigned short* Bhi = (unsigned short*)ws; ws += 65536 * sizeof(unsigned short);
  unsigned short* Blo = (unsigned short*)ws; ws += 65536 * sizeof(unsigned short);
  unsigned short* Bmu = (unsigned short*)ws; ws += 4096 * sizeof(unsigned short);

  hipMemsetAsync(accum, 0, (size_t)5 * NB * sizeof(float), stream);
  returns_kernel<<<(NRET * NB + 255) / 256, 256, 0, stream>>>(inp, pert, ret);
  keys_kernel<<<(NSAMP * NSTEP + 255) / 256, 256, 0, stream>>>(keys);
  pack_kernel<<<(65536 + 4096) / 256, 256, 0, stream>>>(W_hh, w_mu, w_ls, Bhi, Blo, Bmu);
  hist_kernel<<<NB / 32, 256, 0, stream>>>(ret, W_ih, bias, Bhi, Blo, hh, cc);
  mc_kernel<<<NSAMP * (NB / 64), 512, 0, stream>>>(ret, W_ih, bias, Bhi, Blo, Bmu,
      hh, cc, b_mu, b_ls, keys, accum);
  final_kernel<<<NB / 256, 256, 0, stream>>>(accum, (float*)d_out);
}

// Round 11
// 14091.476 us; speedup vs baseline: 4.2122x; 4.2122x over previous
//
#include <hip/hip_runtime.h>
#include <stdint.h>
#include <math.h>

// ---------------------------------------------------------------------------
// Round 11: revert to R9 (best config: 14.7 ms total) with its arch-VGPR
// working set engineered under the immovable 128-reg allocator clamp.
// R10 lesson: the clamp cannot be lifted by waves_per_eu attrs; adding live
// regs (bmu preload + extra acc) causes AGPR-shuffle spills (VALUBusy 31%,
// MfmaUtil 4.7%, 6x regression). R9's only residue was ~8 spilled regs from
// unroll-2's 64 live B regs. Fix:
//  * kb loop unroll 1 + gate-pair B loads (16 live B regs) -> arch ~93 < 128,
//    zero spill; per-tile accumulation order unchanged (same absmax).
//  * wave-0 mu loop unroll 2 (batched loads, shorter serial chain).
// Everything else identical to R9.
// ---------------------------------------------------------------------------

#define HH     128
#define NG     512
#define NB     8192
#define NSAMP  100
#define NSTEP  20
#define TCAP   18
#define NHIST  126
#define NRET   127

using bfrag = __attribute__((ext_vector_type(8))) short;   // 8 bf16 = 4 VGPRs
using facc  = __attribute__((ext_vector_type(16))) float;  // 16 f32 acc

// LDS frag strides (shorts): per-(kb,hs) region 264 (8 pad), per-kb 528.
#define SHS 264
#define SKB 528
#define HFN 4224   // 8 kb * 528

// ----------------------------- threefry2x32 --------------------------------
__device__ __forceinline__ void tf2x32(uint32_t k0, uint32_t k1,
                                       uint32_t x0, uint32_t x1,
                                       uint32_t &y0, uint32_t &y1) {
  uint32_t ks2 = k0 ^ k1 ^ 0x1BD11BDAu;
  x0 += k0; x1 += k1;
#define RR(r) { x0 += x1; x1 = (x1 << (r)) | (x1 >> (32 - (r))); x1 ^= x0; }
  RR(13) RR(15) RR(26) RR(6)   x0 += k1;  x1 += ks2 + 1u;
  RR(17) RR(29) RR(16) RR(24)  x0 += ks2; x1 += k0  + 2u;
  RR(13) RR(15) RR(26) RR(6)   x0 += k0;  x1 += k1  + 3u;
  RR(17) RR(29) RR(16) RR(24)  x0 += k1;  x1 += ks2 + 4u;
  RR(13) RR(15) RR(26) RR(6)   x0 += ks2; x1 += k0  + 5u;
#undef RR
  y0 = x0; y1 = x1;
}

__device__ __forceinline__ float erfinv32(float x) {
  float w = -__logf(fmaxf(1.0f - x * x, 1e-37f));
  float p;
  if (w < 5.0f) {
    w = w - 2.5f;
    p = 2.81022636e-08f;
    p = fmaf(p, w, 3.43273939e-07f);
    p = fmaf(p, w, -3.5233877e-06f);
    p = fmaf(p, w, -4.39150654e-06f);
    p = fmaf(p, w, 0.00021858087f);
    p = fmaf(p, w, -0.00125372503f);
    p = fmaf(p, w, -0.00417768164f);
    p = fmaf(p, w, 0.246640727f);
    p = fmaf(p, w, 1.50140941f);
  } else {
    w = sqrtf(w) - 3.0f;
    p = -0.000200214257f;
    p = fmaf(p, w, 0.000100950558f);
    p = fmaf(p, w, 0.00134934322f);
    p = fmaf(p, w, -0.00367342844f);
    p = fmaf(p, w, 0.00573950773f);
    p = fmaf(p, w, -0.0076224613f);
    p = fmaf(p, w, 0.00943887047f);
    p = fmaf(p, w, 1.00167406f);
    p = fmaf(p, w, 2.83297682f);
  }
  return p * x;
}

__device__ __forceinline__ float normal32(uint32_t k0, uint32_t k1, uint32_t idx) {
  uint32_t y0, y1;
  tf2x32(k0, k1, 0u, idx, y0, y1);
  uint32_t bits = y0 ^ y1;
  float f = __uint_as_float((bits >> 9) | 0x3f800000u) - 1.0f;
  const float lo = __uint_as_float(0xBF7FFFFFu);
  float u = fmaxf(lo, f * 2.0f + lo);
  return 1.41421356f * erfinv32(u);
}

__device__ __forceinline__ float fast_sigmoid(float x) {
  return __builtin_amdgcn_rcpf(1.0f + __expf(-x));
}
__device__ __forceinline__ float fast_tanh(float x) {
  return 1.0f - 2.0f * __builtin_amdgcn_rcpf(1.0f + __expf(2.0f * x));
}

__device__ __forceinline__ unsigned short f2bf(float x) {
  uint32_t u = __float_as_uint(x);
  uint32_t r = u + 0x7fffu + ((u >> 16) & 1u);
  return (unsigned short)(r >> 16);
}
__device__ __forceinline__ float bf2f(unsigned short h) {
  return __uint_as_float(((uint32_t)h) << 16);
}

// ------------------------------- small kernels -----------------------------
__global__ void returns_kernel(const float* __restrict__ inp,
                               const float* __restrict__ pert,
                               float* __restrict__ ret) {
  int i = blockIdx.x * blockDim.x + threadIdx.x;
  if (i >= NRET * NB) return;
  int s = i / NB, b = i - s * NB;
  float p0 = inp[s * NB + b] * (1.0f + pert[s * NB + b]);
  float p1 = inp[(s + 1) * NB + b] * (1.0f + pert[(s + 1) * NB + b]);
  ret[i] = p1 - p0;
}

__global__ void keys_kernel(uint32_t* __restrict__ keys) {
  int id = blockIdx.x * blockDim.x + threadIdx.x;
  if (id >= NSAMP * NSTEP) return;
  int s = id / NSTEP, t = id - s * NSTEP;
  uint32_t sk0, sk1, k0, k1;
  tf2x32(0u, 42u, 0u, (uint32_t)s, sk0, sk1);
  tf2x32(sk0, sk1, 0u, (uint32_t)t, k0, k1);
  keys[2 * id] = k0; keys[2 * id + 1] = k1;
}

// B-fragment pack: Bhi/Blo[((gct*8+kb)*64+lane)*8+j]
//   k = kb*16 + 8*(lane>>5) + j, g = 32*gct + (lane&31).
__global__ void pack_kernel(const float* __restrict__ W_hh,
                            const float* __restrict__ w_mu,
                            const float* __restrict__ w_ls,
                            unsigned short* __restrict__ Bhi,
                            unsigned short* __restrict__ Blo,
                            unsigned short* __restrict__ Bmu) {
  int idx = blockIdx.x * blockDim.x + threadIdx.x;
  if (idx < 65536) {
    int j = idx & 7, lane = (idx >> 3) & 63, kb = (idx >> 9) & 7, gct = idx >> 12;
    int k = kb * 16 + ((lane >> 5) << 3) + j;
    int g = (gct << 5) + (lane & 31);
    float w = W_hh[k * NG + g];
    unsigned short hi = f2bf(w);
    unsigned short lo = f2bf(w - bf2f(hi));
    Bhi[idx] = hi; Blo[idx] = lo;
  } else if (idx < 65536 + 4096) {
    int i2 = idx - 65536;
    int j = i2 & 7, lane = (i2 >> 3) & 63, kb = (i2 >> 9) & 7;
    int k = kb * 16 + ((lane >> 5) << 3) + j;
    int col = lane & 31;
    float v = (col == 0) ? w_mu[k] : (col == 1 ? w_ls[k] : 0.0f);
    Bmu[i2] = f2bf(v);
  }
}

// ------------------------------ main LSTM kernel ---------------------------
// RT=2 (mc): 512 thr = 8 waves, 64 rows; wave w: cg=w>>1, rt=w&1; 4 acc
//   tiles (64 AGPR). 512-thr block forces 2 waves/SIMD co-residency.
// RT=1 (hist): 256 thr = 4 waves, 32 rows; wave w: cg=w, rt=0.
template<int RT, bool STOCH>
__launch_bounds__(RT * 256, 1)
__global__ void lstm_kernel(const float* __restrict__ ret,
                            const float* __restrict__ W_ih,
                            const float* __restrict__ bias,
                            const unsigned short* __restrict__ Bhi,
                            const unsigned short* __restrict__ Blo,
                            const unsigned short* __restrict__ Bmu,
                            const float* __restrict__ hin,
                            const float* __restrict__ cin,
                            float* __restrict__ hout,
                            float* __restrict__ cout,
                            const float* __restrict__ b_mu,
                            const float* __restrict__ b_ls,
                            const uint32_t* __restrict__ keys,
                            float* __restrict__ accum) {
  __shared__ unsigned short hfh[2][RT][HFN];
  __shared__ unsigned short hfl[2][RT][HFN];
  __shared__ float x_s[64];
  __shared__ float mu_s[64];
  __shared__ float ls_s[64];

  const int tid  = threadIdx.x;
  const int lane = tid & 63;
  const int w    = tid >> 6;
  const int cg   = (RT == 2) ? (w >> 1) : w;
  const int rt   = (RT == 2) ? (w & 1) : 0;
  const int hs   = lane >> 5;
  const int m    = lane & 31;
  const int col  = (cg << 5) + m;

  int s, b0;
  if (STOCH) { s = blockIdx.x >> 7; b0 = (blockIdx.x & 127) << 6; }
  else       { s = 0;               b0 = blockIdx.x << 5; }   // 32 rows (RT=1)

  float wih_r[4], bb_r[4];
#pragma unroll
  for (int gi = 0; gi < 4; ++gi) {
    wih_r[gi] = W_ih[(gi << 7) + col];
    bb_r[gi]  = bias[(gi << 7) + col];
  }
  const float bmu = b_mu[0], bls = b_ls[0];

  // swizzled frag offsets: write (lane's col), read (lane's m,hs)
  const int coff = (col >> 4) * SKB + ((col >> 3) & 1) * SHS + (col & 7);
  const int aoff = hs * SHS + m * 8;

  // ---- init h frags (buf 0) + c registers (this wave's rt tile)
  float c_reg[16];
#pragma unroll
  for (int reg = 0; reg < 16; ++reg) {
    int row32 = (reg & 3) + ((reg >> 2) << 3) + (hs << 2);
    float hv = 0.0f, cv = 0.0f;
    if (STOCH) {
      int grow = b0 + (rt << 5) + row32;
      hv = hin[grow * HH + col];
      cv = cin[grow * HH + col];
    }
    c_reg[reg] = cv;
    unsigned short hi = f2bf(hv);
    unsigned short lo = f2bf(hv - bf2f(hi));
    hfh[0][rt][coff + row32 * 8] = hi;
    hfl[0][rt][coff + row32 * 8] = lo;
  }
  if (STOCH && tid < 64) x_s[tid] = ret[126 * NB + b0 + tid];
  float logw = 0.0f, outv = 0.0f;
  __syncthreads();

  const int nsteps = STOCH ? NSTEP : NHIST;
  int buf = 0;
#pragma unroll 1
  for (int t = 0; t < nsteps; ++t) {
    const int nbuf = buf ^ 1;

    // ---- C init: x*W_ih + b (fp32 exact)
    facc acc[4];
#pragma unroll
    for (int reg = 0; reg < 16; ++reg) {
      int row32 = (reg & 3) + ((reg >> 2) << 3) + (hs << 2);
      float xv;
      if (STOCH) xv = x_s[(rt << 5) + row32];
      else       xv = ret[t * NB + b0 + row32];
#pragma unroll
      for (int gi = 0; gi < 4; ++gi)
        acc[gi][reg] = fmaf(xv, wih_r[gi], bb_r[gi]);
    }

    // ---- gate matmul: 3-term split-bf16, 96 MFMAs/wave.
    // unroll 1 + gate-pair B loads: live B = 16 regs -> arch set ~93 < the
    // 128-reg allocator clamp -> zero spill (R9 spilled ~8 regs here).
#pragma unroll 1
    for (int kb = 0; kb < 8; ++kb) {
      bfrag ah = *(const bfrag*)&hfh[buf][rt][kb * SKB + aoff];
      bfrag al = *(const bfrag*)&hfl[buf][rt][kb * SKB + aoff];
#pragma unroll
      for (int gp = 0; gp < 2; ++gp) {
        const int g0 = 2 * gp, g1 = 2 * gp + 1;
        const int off0 = ((((g0 << 2) + cg) << 3) + kb) * 512 + lane * 8;
        const int off1 = ((((g1 << 2) + cg) << 3) + kb) * 512 + lane * 8;
        bfrag bh0 = *(const bfrag*)&Bhi[off0];
        bfrag bl0 = *(const bfrag*)&Blo[off0];
        bfrag bh1 = *(const bfrag*)&Bhi[off1];
        bfrag bl1 = *(const bfrag*)&Blo[off1];
        // per-tile order: hh, lh, hl (matches all prior rounds)
        acc[g0] = __builtin_amdgcn_mfma_f32_32x32x16_bf16(ah, bh0, acc[g0], 0, 0, 0);
        acc[g1] = __builtin_amdgcn_mfma_f32_32x32x16_bf16(ah, bh1, acc[g1], 0, 0, 0);
        acc[g0] = __builtin_amdgcn_mfma_f32_32x32x16_bf16(al, bh0, acc[g0], 0, 0, 0);
        acc[g1] = __builtin_amdgcn_mfma_f32_32x32x16_bf16(al, bh1, acc[g1], 0, 0, 0);
        acc[g0] = __builtin_amdgcn_mfma_f32_32x32x16_bf16(ah, bl0, acc[g0], 0, 0, 0);
        acc[g1] = __builtin_amdgcn_mfma_f32_32x32x16_bf16(ah, bl1, acc[g1], 0, 0, 0);
      }
    }

    // ---- epilogue: cell update, swizzled (conflict-free) frag writes
#pragma unroll
    for (int reg = 0; reg < 16; ++reg) {
      int row32 = (reg & 3) + ((reg >> 2) << 3) + (hs << 2);
      float ig = fast_sigmoid(acc[0][reg]);
      float fg = fast_sigmoid(acc[1][reg]);
      float gg = fast_tanh  (acc[2][reg]);
      float og = fast_sigmoid(acc[3][reg]);
      float c  = fmaf(fg, c_reg[reg], ig * gg);
      c_reg[reg] = c;
      float h  = og * fast_tanh(c);
      unsigned short hi = f2bf(h);
      unsigned short lo = f2bf(h - bf2f(hi));
      hfh[nbuf][rt][coff + row32 * 8] = hi;
      hfl[nbuf][rt][coff + row32 * 8] = lo;
      if (!STOCH && t == NHIST - 1)
        hout[(b0 + row32) * HH + col] = h;
    }
    __syncthreads();   // B1: nbuf writes visible; old-buf reads done

    if (STOCH) {
      if (tid < 64) {   // wave 0 only: mu/ls MFMA (both rt tiles) + RNG
        facc am[2];
#pragma unroll
        for (int rr = 0; rr < 2; ++rr)
#pragma unroll
          for (int e = 0; e < 16; ++e) am[rr][e] = 0.0f;
#pragma unroll 2
        for (int kb = 0; kb < 8; ++kb) {
          const bfrag bm = *(const bfrag*)&Bmu[kb * 512 + lane * 8];
          const bfrag a0 = *(const bfrag*)&hfh[nbuf][0][kb * SKB + aoff];
          const bfrag a1 = *(const bfrag*)&hfh[nbuf][RT == 2 ? 1 : 0][kb * SKB + aoff];
          am[0] = __builtin_amdgcn_mfma_f32_32x32x16_bf16(a0, bm, am[0], 0, 0, 0);
          am[1] = __builtin_amdgcn_mfma_f32_32x32x16_bf16(a1, bm, am[1], 0, 0, 0);
        }
        if (m < 2) {
          float* dst = (m == 0) ? mu_s : ls_s;
#pragma unroll
          for (int rr = 0; rr < 2; ++rr)
#pragma unroll
            for (int reg = 0; reg < 16; ++reg)
              dst[(rr << 5) + (reg & 3) + ((reg >> 2) << 3) + (hs << 2)] = am[rr][reg];
        }
        // same-wave LDS RAW: compiler inserts lgkmcnt wait
        float mu  = mu_s[lane] + bmu;
        float lsc = fminf(fmaxf(ls_s[lane] + bls, -5.0f), 2.0f);
        float sg  = __expf(lsc);
        uint32_t k0 = keys[2 * (s * NSTEP + t)];
        uint32_t k1 = keys[2 * (s * NSTEP + t) + 1];
        float z  = normal32(k0, k1, (uint32_t)(b0 + lane));
        float xn = fmaf(sg, z + 0.5f, mu);
        logw -= fmaf(0.5f, z, 0.125f);
        if (t == TCAP) outv = xn;
        x_s[lane] = xn;
      }
      __syncthreads();  // B2: x_s ready
    }
    buf = nbuf;
  }

  if (STOCH) {
    if (tid < 64) {
      float wt = __expf(logw);
      float ow = outv * wt;
      int b = b0 + lane;
      atomicAdd(&accum[0 * NB + b], wt);
      atomicAdd(&accum[1 * NB + b], ow);
      atomicAdd(&accum[2 * NB + b], wt * wt);
      atomicAdd(&accum[3 * NB + b], ow * ow);
      atomicAdd(&accum[4 * NB + b], outv * wt * wt);
    }
  } else {
#pragma unroll
    for (int reg = 0; reg < 16; ++reg) {
      int row32 = (reg & 3) + ((reg >> 2) << 3) + (hs << 2);
      cout[(b0 + row32) * HH + col] = c_reg[reg];
    }
  }
}

// ------------------------------- final kernel ------------------------------
__global__ void final_kernel(const float* __restrict__ accum,
                             float* __restrict__ out) {
  int b = blockIdx.x * blockDim.x + threadIdx.x;
  if (b >= NB) return;
  float sw  = accum[0 * NB + b];
  float sm1 = accum[1 * NB + b];
  float sqw = accum[2 * NB + b];
  float sm2 = accum[3 * NB + b];
  float shm = accum[4 * NB + b];
  float mean = sm1 / sw;
  float sem = sm2 + sqw * mean * mean - 2.0f * shm * mean;
  sem = sqrtf(sem / (float)(NSAMP * (NSAMP - 1)));
  out[b] = mean;
  out[NB + b] = sem;
}

// ------------------------------- launcher ----------------------------------
extern "C" void kernel_launch(void* const* d_in, const int* in_sizes, int n_in,
                              void* d_out, int out_size, void* d_ws, size_t ws_size,
                              hipStream_t stream) {
  (void)in_sizes; (void)n_in; (void)out_size; (void)ws_size;
  const float* inp  = (const float*)d_in[0];
  const float* pert = (const float*)d_in[1];
  const float* W_ih = (const float*)d_in[2];
  const float* W_hh = (const float*)d_in[3];
  const float* bias = (const float*)d_in[4];
  const float* w_mu = (const float*)d_in[5];
  const float* b_mu = (const float*)d_in[6];
  const float* w_ls = (const float*)d_in[7];
  const float* b_ls = (const float*)d_in[8];

  char* ws = (char*)d_ws;
  float* ret = (float*)ws;        ws += (size_t)NRET * NB * sizeof(float);
  float* hh  = (float*)ws;        ws += (size_t)NB * HH * sizeof(float);
  float* cc  = (float*)ws;        ws += (size_t)NB * HH * sizeof(float);
  uint32_t* keys = (uint32_t*)ws; ws += (size_t)NSAMP * NSTEP * 2 * sizeof(uint32_t);
  float* accum = (float*)ws;      ws += (size_t)5 * NB * sizeof(float);
  unsigned short* Bhi = (unsigned short*)ws; ws += 65536 * sizeof(unsigned short);
  unsigned short* Blo = (unsigned short*)ws; ws += 65536 * sizeof(unsigned short);
  unsigned short* Bmu = (unsigned short*)ws; ws += 4096 * sizeof(unsigned short);

  hipMemsetAsync(accum, 0, (size_t)5 * NB * sizeof(float), stream);
  returns_kernel<<<(NRET * NB + 255) / 256, 256, 0, stream>>>(inp, pert, ret);
  keys_kernel<<<(NSAMP * NSTEP + 255) / 256, 256, 0, stream>>>(keys);
  pack_kernel<<<(65536 + 4096) / 256, 256, 0, stream>>>(W_hh, w_mu, w_ls, Bhi, Blo, Bmu);
  lstm_kernel<1, false><<<NB / 32, 256, 0, stream>>>(ret, W_ih, bias, Bhi, Blo, Bmu,
      nullptr, nullptr, hh, cc, b_mu, b_ls, keys, nullptr);
  lstm_kernel<2, true><<<NSAMP * (NB / 64), 512, 0, stream>>>(ret, W_ih, bias, Bhi, Blo, Bmu,
      hh, cc, nullptr, nullptr, b_mu, b_ls, keys, accum);
  final_kernel<<<NB / 256, 256, 0, stream>>>(accum, (float*)d_out);
}

// Round 12
// 9611.472 us; speedup vs baseline: 6.1755x; 1.4661x over previous
//
#include <hip/hip_runtime.h>
#include <stdint.h>
#include <math.h>

// ---------------------------------------------------------------------------
// Round 12: 3 waves/SIMD. R11's wall arithmetic: per block-step ~31k cyc vs
// ~8k issue -> 80% latency stall at 2 waves/SIMD (unified 192/wave: 64 AGPR
// + 128 arch). 3 waves/SIMD needs <=170 unified = 64 AGPR + <=106 arch.
//  * mc: 256 thr / 4 waves / 32 rows (wave=cg, 4 acc tiles=64 AGPR), same
//    inner loop as R11's RT=1 path (arch ~95).
//  * LDS 68.6 -> ~26 KB: hfh double-buffered (gate A + mu-MFMA reads), hfl
//    single-buffered. Safe because B1 moved between matmul-reads and
//    epilogue-writes, and x*W_ih+b folded into the epilogue (kb loop no
//    longer reads x_s; x_s written by wave0 after B2 is visible to epilogue
//    consumers via next step's B1). Still 2 barriers/step.
//  * __launch_bounds__(256,3): target 3 blocks/CU = 12 waves/CU (LDS 78 KB).
// ---------------------------------------------------------------------------

#define HH     128
#define NG     512
#define NB     8192
#define NSAMP  100
#define NSTEP  20
#define TCAP   18
#define NHIST  126
#define NRET   127

using bfrag = __attribute__((ext_vector_type(8))) short;   // 8 bf16 = 4 VGPRs
using facc  = __attribute__((ext_vector_type(16))) float;  // 16 f32 acc

// LDS frag strides (shorts): per-(kb,hs) region 264 (8 pad), per-kb 528.
#define SHS 264
#define SKB 528
#define HFN 4224   // 8 kb * 528

// ----------------------------- threefry2x32 --------------------------------
__device__ __forceinline__ void tf2x32(uint32_t k0, uint32_t k1,
                                       uint32_t x0, uint32_t x1,
                                       uint32_t &y0, uint32_t &y1) {
  uint32_t ks2 = k0 ^ k1 ^ 0x1BD11BDAu;
  x0 += k0; x1 += k1;
#define RR(r) { x0 += x1; x1 = (x1 << (r)) | (x1 >> (32 - (r))); x1 ^= x0; }
  RR(13) RR(15) RR(26) RR(6)   x0 += k1;  x1 += ks2 + 1u;
  RR(17) RR(29) RR(16) RR(24)  x0 += ks2; x1 += k0  + 2u;
  RR(13) RR(15) RR(26) RR(6)   x0 += k0;  x1 += k1  + 3u;
  RR(17) RR(29) RR(16) RR(24)  x0 += k1;  x1 += ks2 + 4u;
  RR(13) RR(15) RR(26) RR(6)   x0 += ks2; x1 += k0  + 5u;
#undef RR
  y0 = x0; y1 = x1;
}

__device__ __forceinline__ float erfinv32(float x) {
  float w = -__logf(fmaxf(1.0f - x * x, 1e-37f));
  float p;
  if (w < 5.0f) {
    w = w - 2.5f;
    p = 2.81022636e-08f;
    p = fmaf(p, w, 3.43273939e-07f);
    p = fmaf(p, w, -3.5233877e-06f);
    p = fmaf(p, w, -4.39150654e-06f);
    p = fmaf(p, w, 0.00021858087f);
    p = fmaf(p, w, -0.00125372503f);
    p = fmaf(p, w, -0.00417768164f);
    p = fmaf(p, w, 0.246640727f);
    p = fmaf(p, w, 1.50140941f);
  } else {
    w = sqrtf(w) - 3.0f;
    p = -0.000200214257f;
    p = fmaf(p, w, 0.000100950558f);
    p = fmaf(p, w, 0.00134934322f);
    p = fmaf(p, w, -0.00367342844f);
    p = fmaf(p, w, 0.00573950773f);
    p = fmaf(p, w, -0.0076224613f);
    p = fmaf(p, w, 0.00943887047f);
    p = fmaf(p, w, 1.00167406f);
    p = fmaf(p, w, 2.83297682f);
  }
  return p * x;
}

__device__ __forceinline__ float normal32(uint32_t k0, uint32_t k1, uint32_t idx) {
  uint32_t y0, y1;
  tf2x32(k0, k1, 0u, idx, y0, y1);
  uint32_t bits = y0 ^ y1;
  float f = __uint_as_float((bits >> 9) | 0x3f800000u) - 1.0f;
  const float lo = __uint_as_float(0xBF7FFFFFu);
  float u = fmaxf(lo, f * 2.0f + lo);
  return 1.41421356f * erfinv32(u);
}

__device__ __forceinline__ float fast_sigmoid(float x) {
  return __builtin_amdgcn_rcpf(1.0f + __expf(-x));
}
__device__ __forceinline__ float fast_tanh(float x) {
  return 1.0f - 2.0f * __builtin_amdgcn_rcpf(1.0f + __expf(2.0f * x));
}

__device__ __forceinline__ unsigned short f2bf(float x) {
  uint32_t u = __float_as_uint(x);
  uint32_t r = u + 0x7fffu + ((u >> 16) & 1u);
  return (unsigned short)(r >> 16);
}
__device__ __forceinline__ float bf2f(unsigned short h) {
  return __uint_as_float(((uint32_t)h) << 16);
}

// ------------------------------- small kernels -----------------------------
__global__ void returns_kernel(const float* __restrict__ inp,
                               const float* __restrict__ pert,
                               float* __restrict__ ret) {
  int i = blockIdx.x * blockDim.x + threadIdx.x;
  if (i >= NRET * NB) return;
  int s = i / NB, b = i - s * NB;
  float p0 = inp[s * NB + b] * (1.0f + pert[s * NB + b]);
  float p1 = inp[(s + 1) * NB + b] * (1.0f + pert[(s + 1) * NB + b]);
  ret[i] = p1 - p0;
}

__global__ void keys_kernel(uint32_t* __restrict__ keys) {
  int id = blockIdx.x * blockDim.x + threadIdx.x;
  if (id >= NSAMP * NSTEP) return;
  int s = id / NSTEP, t = id - s * NSTEP;
  uint32_t sk0, sk1, k0, k1;
  tf2x32(0u, 42u, 0u, (uint32_t)s, sk0, sk1);
  tf2x32(sk0, sk1, 0u, (uint32_t)t, k0, k1);
  keys[2 * id] = k0; keys[2 * id + 1] = k1;
}

// B-fragment pack: Bhi/Blo[((gct*8+kb)*64+lane)*8+j]
//   k = kb*16 + 8*(lane>>5) + j, g = 32*gct + (lane&31).
__global__ void pack_kernel(const float* __restrict__ W_hh,
                            const float* __restrict__ w_mu,
                            const float* __restrict__ w_ls,
                            unsigned short* __restrict__ Bhi,
                            unsigned short* __restrict__ Blo,
                            unsigned short* __restrict__ Bmu) {
  int idx = blockIdx.x * blockDim.x + threadIdx.x;
  if (idx < 65536) {
    int j = idx & 7, lane = (idx >> 3) & 63, kb = (idx >> 9) & 7, gct = idx >> 12;
    int k = kb * 16 + ((lane >> 5) << 3) + j;
    int g = (gct << 5) + (lane & 31);
    float w = W_hh[k * NG + g];
    unsigned short hi = f2bf(w);
    unsigned short lo = f2bf(w - bf2f(hi));
    Bhi[idx] = hi; Blo[idx] = lo;
  } else if (idx < 65536 + 4096) {
    int i2 = idx - 65536;
    int j = i2 & 7, lane = (i2 >> 3) & 63, kb = (i2 >> 9) & 7;
    int k = kb * 16 + ((lane >> 5) << 3) + j;
    int col = lane & 31;
    float v = (col == 0) ? w_mu[k] : (col == 1 ? w_ls[k] : 0.0f);
    Bmu[i2] = f2bf(v);
  }
}

// ------------------------------ history kernel -----------------------------
// 256 thr = 4 waves; wave cg owns 32 hidden cols x 4 gates, 32 rows/block.
__launch_bounds__(256, 1)
__global__ void hist_kernel(const float* __restrict__ ret,
                            const float* __restrict__ W_ih,
                            const float* __restrict__ bias,
                            const unsigned short* __restrict__ Bhi,
                            const unsigned short* __restrict__ Blo,
                            float* __restrict__ hout,
                            float* __restrict__ cout) {
  __shared__ unsigned short hfh[2][HFN];
  __shared__ unsigned short hfl[2][HFN];

  const int tid  = threadIdx.x;
  const int lane = tid & 63;
  const int cg   = tid >> 6;
  const int hs   = lane >> 5;
  const int m    = lane & 31;
  const int col  = (cg << 5) + m;
  const int b0   = blockIdx.x << 5;

  float wih_r[4], bb_r[4];
#pragma unroll
  for (int gi = 0; gi < 4; ++gi) {
    wih_r[gi] = W_ih[(gi << 7) + col];
    bb_r[gi]  = bias[(gi << 7) + col];
  }

  const int coff = (col >> 4) * SKB + ((col >> 3) & 1) * SHS + (col & 7);
  const int aoff = hs * SHS + m * 8;

  float c_reg[16];
#pragma unroll
  for (int reg = 0; reg < 16; ++reg) {
    int row32 = (reg & 3) + ((reg >> 2) << 3) + (hs << 2);
    c_reg[reg] = 0.0f;
    hfh[0][coff + row32 * 8] = 0;
    hfl[0][coff + row32 * 8] = 0;
  }
  __syncthreads();

  int buf = 0;
#pragma unroll 1
  for (int t = 0; t < NHIST; ++t) {
    const int nbuf = buf ^ 1;
    facc acc[4];
#pragma unroll
    for (int reg = 0; reg < 16; ++reg) {
      int row32 = (reg & 3) + ((reg >> 2) << 3) + (hs << 2);
      float xv = ret[t * NB + b0 + row32];
#pragma unroll
      for (int gi = 0; gi < 4; ++gi)
        acc[gi][reg] = fmaf(xv, wih_r[gi], bb_r[gi]);
    }
#pragma unroll 1
    for (int kb = 0; kb < 8; ++kb) {
      bfrag ah = *(const bfrag*)&hfh[buf][kb * SKB + aoff];
      bfrag al = *(const bfrag*)&hfl[buf][kb * SKB + aoff];
#pragma unroll
      for (int gp = 0; gp < 2; ++gp) {
        const int g0 = 2 * gp, g1 = 2 * gp + 1;
        const int off0 = ((((g0 << 2) + cg) << 3) + kb) * 512 + lane * 8;
        const int off1 = ((((g1 << 2) + cg) << 3) + kb) * 512 + lane * 8;
        bfrag bh0 = *(const bfrag*)&Bhi[off0];
        bfrag bl0 = *(const bfrag*)&Blo[off0];
        bfrag bh1 = *(const bfrag*)&Bhi[off1];
        bfrag bl1 = *(const bfrag*)&Blo[off1];
        acc[g0] = __builtin_amdgcn_mfma_f32_32x32x16_bf16(ah, bh0, acc[g0], 0, 0, 0);
        acc[g1] = __builtin_amdgcn_mfma_f32_32x32x16_bf16(ah, bh1, acc[g1], 0, 0, 0);
        acc[g0] = __builtin_amdgcn_mfma_f32_32x32x16_bf16(al, bh0, acc[g0], 0, 0, 0);
        acc[g1] = __builtin_amdgcn_mfma_f32_32x32x16_bf16(al, bh1, acc[g1], 0, 0, 0);
        acc[g0] = __builtin_amdgcn_mfma_f32_32x32x16_bf16(ah, bl0, acc[g0], 0, 0, 0);
        acc[g1] = __builtin_amdgcn_mfma_f32_32x32x16_bf16(ah, bl1, acc[g1], 0, 0, 0);
      }
    }
#pragma unroll
    for (int reg = 0; reg < 16; ++reg) {
      int row32 = (reg & 3) + ((reg >> 2) << 3) + (hs << 2);
      float ig = fast_sigmoid(acc[0][reg]);
      float fg = fast_sigmoid(acc[1][reg]);
      float gg = fast_tanh  (acc[2][reg]);
      float og = fast_sigmoid(acc[3][reg]);
      float c  = fmaf(fg, c_reg[reg], ig * gg);
      c_reg[reg] = c;
      float h  = og * fast_tanh(c);
      unsigned short hi = f2bf(h);
      unsigned short lo = f2bf(h - bf2f(hi));
      hfh[nbuf][coff + row32 * 8] = hi;
      hfl[nbuf][coff + row32 * 8] = lo;
      if (t == NHIST - 1) {
        hout[(b0 + row32) * HH + col] = h;
        cout[(b0 + row32) * HH + col] = c;
      }
    }
    __syncthreads();
    buf = nbuf;
  }
}

// -------------------------------- MC kernel --------------------------------
// 256 thr = 4 waves, 32 rows/block; wave cg owns 32 hidden cols x 4 gates
// (4 acc tiles = 64 AGPR). hfh double-buffered, hfl single. Two barriers:
//   kb-matmul(reads) -> B1 -> epilogue(x-fold + writes) -> B2 -> wave0 RNG.
__launch_bounds__(256, 3)
__global__ void mc_kernel(const float* __restrict__ ret,
                          const float* __restrict__ W_ih,
                          const float* __restrict__ bias,
                          const unsigned short* __restrict__ Bhi,
                          const unsigned short* __restrict__ Blo,
                          const unsigned short* __restrict__ Bmu,
                          const float* __restrict__ hin,
                          const float* __restrict__ cin,
                          const float* __restrict__ b_mu,
                          const float* __restrict__ b_ls,
                          const uint32_t* __restrict__ keys,
                          float* __restrict__ accum) {
  __shared__ unsigned short hfh[2][HFN];
  __shared__ unsigned short hfl[HFN];
  __shared__ float x_s[32];
  __shared__ float mu_s[32];
  __shared__ float ls_s[32];

  const int tid  = threadIdx.x;
  const int lane = tid & 63;
  const int cg   = tid >> 6;
  const int hs   = lane >> 5;
  const int m    = lane & 31;
  const int col  = (cg << 5) + m;

  const int s  = blockIdx.x >> 8;
  const int b0 = (blockIdx.x & 255) << 5;

  float wih_r[4], bb_r[4];
#pragma unroll
  for (int gi = 0; gi < 4; ++gi) {
    wih_r[gi] = W_ih[(gi << 7) + col];
    bb_r[gi]  = bias[(gi << 7) + col];
  }
  const float bmu = b_mu[0], bls = b_ls[0];

  const int coff = (col >> 4) * SKB + ((col >> 3) & 1) * SHS + (col & 7);
  const int aoff = hs * SHS + m * 8;

  // init h frags + c regs
  float c_reg[16];
#pragma unroll
  for (int reg = 0; reg < 16; ++reg) {
    int row32 = (reg & 3) + ((reg >> 2) << 3) + (hs << 2);
    int grow = b0 + row32;
    float hv = hin[grow * HH + col];
    c_reg[reg] = cin[grow * HH + col];
    unsigned short hi = f2bf(hv);
    unsigned short lo = f2bf(hv - bf2f(hi));
    hfh[0][coff + row32 * 8] = hi;
    hfl[coff + row32 * 8] = lo;
  }
  if (tid < 32) x_s[tid] = ret[126 * NB + b0 + tid];
  float logw = 0.0f, outv = 0.0f;
  __syncthreads();

  int buf = 0;
#pragma unroll 1
  for (int t = 0; t < NSTEP; ++t) {
    const int nbuf = buf ^ 1;

    // ---- gate matmul from h_t (hfh[buf], hfl); acc starts at 0
    facc acc[4];
#pragma unroll
    for (int gi = 0; gi < 4; ++gi)
#pragma unroll
      for (int e = 0; e < 16; ++e) acc[gi][e] = 0.0f;
#pragma unroll 1
    for (int kb = 0; kb < 8; ++kb) {
      bfrag ah = *(const bfrag*)&hfh[buf][kb * SKB + aoff];
      bfrag al = *(const bfrag*)&hfl[kb * SKB + aoff];
#pragma unroll
      for (int gp = 0; gp < 2; ++gp) {
        const int g0 = 2 * gp, g1 = 2 * gp + 1;
        const int off0 = ((((g0 << 2) + cg) << 3) + kb) * 512 + lane * 8;
        const int off1 = ((((g1 << 2) + cg) << 3) + kb) * 512 + lane * 8;
        bfrag bh0 = *(const bfrag*)&Bhi[off0];
        bfrag bl0 = *(const bfrag*)&Blo[off0];
        bfrag bh1 = *(const bfrag*)&Bhi[off1];
        bfrag bl1 = *(const bfrag*)&Blo[off1];
        acc[g0] = __builtin_amdgcn_mfma_f32_32x32x16_bf16(ah, bh0, acc[g0], 0, 0, 0);
        acc[g1] = __builtin_amdgcn_mfma_f32_32x32x16_bf16(ah, bh1, acc[g1], 0, 0, 0);
        acc[g0] = __builtin_amdgcn_mfma_f32_32x32x16_bf16(al, bh0, acc[g0], 0, 0, 0);
        acc[g1] = __builtin_amdgcn_mfma_f32_32x32x16_bf16(al, bh1, acc[g1], 0, 0, 0);
        acc[g0] = __builtin_amdgcn_mfma_f32_32x32x16_bf16(ah, bl0, acc[g0], 0, 0, 0);
        acc[g1] = __builtin_amdgcn_mfma_f32_32x32x16_bf16(ah, bl1, acc[g1], 0, 0, 0);
      }
    }
    __syncthreads();   // B1: all hfh[buf]/hfl reads done; x_s(t) visible

    // ---- epilogue: fold x*W_ih+b, activations, write hfh[nbuf] + hfl
#pragma unroll
    for (int reg = 0; reg < 16; ++reg) {
      int row32 = (reg & 3) + ((reg >> 2) << 3) + (hs << 2);
      float xv = x_s[row32];
      float ig = fast_sigmoid(acc[0][reg] + fmaf(xv, wih_r[0], bb_r[0]));
      float fg = fast_sigmoid(acc[1][reg] + fmaf(xv, wih_r[1], bb_r[1]));
      float gg = fast_tanh  (acc[2][reg] + fmaf(xv, wih_r[2], bb_r[2]));
      float og = fast_sigmoid(acc[3][reg] + fmaf(xv, wih_r[3], bb_r[3]));
      float c  = fmaf(fg, c_reg[reg], ig * gg);
      c_reg[reg] = c;
      float h  = og * fast_tanh(c);
      unsigned short hi = f2bf(h);
      unsigned short lo = f2bf(h - bf2f(hi));
      hfh[nbuf][coff + row32 * 8] = hi;
      hfl[coff + row32 * 8] = lo;
    }
    __syncthreads();   // B2: h(t+1) frags visible

    if (tid < 64) {    // wave 0: mu/ls MFMA on hfh[nbuf] + RNG + x_s(t+1)
      facc am;
#pragma unroll
      for (int e = 0; e < 16; ++e) am[e] = 0.0f;
#pragma unroll 2
      for (int kb = 0; kb < 8; ++kb) {
        const bfrag bm = *(const bfrag*)&Bmu[kb * 512 + lane * 8];
        const bfrag a0 = *(const bfrag*)&hfh[nbuf][kb * SKB + aoff];
        am = __builtin_amdgcn_mfma_f32_32x32x16_bf16(a0, bm, am, 0, 0, 0);
      }
      if (m < 2) {
        float* dst = (m == 0) ? mu_s : ls_s;
#pragma unroll
        for (int reg = 0; reg < 16; ++reg)
          dst[(reg & 3) + ((reg >> 2) << 3) + (hs << 2)] = am[reg];
      }
      // same-wave LDS RAW: compiler inserts lgkmcnt wait
      float mu  = mu_s[m] + bmu;
      float lsc = fminf(fmaxf(ls_s[m] + bls, -5.0f), 2.0f);
      float sg  = __expf(lsc);
      uint32_t k0 = keys[2 * (s * NSTEP + t)];
      uint32_t k1 = keys[2 * (s * NSTEP + t) + 1];
      float z  = normal32(k0, k1, (uint32_t)(b0 + m));
      float xn = fmaf(sg, z + 0.5f, mu);
      logw -= fmaf(0.5f, z, 0.125f);
      if (t == TCAP) outv = xn;
      if (lane < 32) x_s[lane] = xn;   // visible to consumers via next B1
    }
    buf = nbuf;
  }

  if (tid < 32) {
    float wt = __expf(logw);
    float ow = outv * wt;
    int b = b0 + tid;
    atomicAdd(&accum[0 * NB + b], wt);
    atomicAdd(&accum[1 * NB + b], ow);
    atomicAdd(&accum[2 * NB + b], wt * wt);
    atomicAdd(&accum[3 * NB + b], ow * ow);
    atomicAdd(&accum[4 * NB + b], outv * wt * wt);
  }
}

// ------------------------------- final kernel ------------------------------
__global__ void final_kernel(const float* __restrict__ accum,
                             float* __restrict__ out) {
  int b = blockIdx.x * blockDim.x + threadIdx.x;
  if (b >= NB) return;
  float sw  = accum[0 * NB + b];
  float sm1 = accum[1 * NB + b];
  float sqw = accum[2 * NB + b];
  float sm2 = accum[3 * NB + b];
  float shm = accum[4 * NB + b];
  float mean = sm1 / sw;
  float sem = sm2 + sqw * mean * mean - 2.0f * shm * mean;
  sem = sqrtf(sem / (float)(NSAMP * (NSAMP - 1)));
  out[b] = mean;
  out[NB + b] = sem;
}

// ------------------------------- launcher ----------------------------------
extern "C" void kernel_launch(void* const* d_in, const int* in_sizes, int n_in,
                              void* d_out, int out_size, void* d_ws, size_t ws_size,
                              hipStream_t stream) {
  (void)in_sizes; (void)n_in; (void)out_size; (void)ws_size;
  const float* inp  = (const float*)d_in[0];
  const float* pert = (const float*)d_in[1];
  const float* W_ih = (const float*)d_in[2];
  const float* W_hh = (const float*)d_in[3];
  const float* bias = (const float*)d_in[4];
  const float* w_mu = (const float*)d_in[5];
  const float* b_mu = (const float*)d_in[6];
  const float* w_ls = (const float*)d_in[7];
  const float* b_ls = (const float*)d_in[8];

  char* ws = (char*)d_ws;
  float* ret = (float*)ws;        ws += (size_t)NRET * NB * sizeof(float);
  float* hh  = (float*)ws;        ws += (size_t)NB * HH * sizeof(float);
  float* cc  = (float*)ws;        ws += (size_t)NB * HH * sizeof(float);
  uint32_t* keys = (uint32_t*)ws; ws += (size_t)NSAMP * NSTEP * 2 * sizeof(uint32_t);
  float* accum = (float*)ws;      ws += (size_t)5 * NB * sizeof(float);
  unsigned short* Bhi = (unsigned short*)ws; ws += 65536 * sizeof(unsigned short);
  unsigned short* Blo = (unsigned short*)ws; ws += 65536 * sizeof(unsigned short);
  unsigned short* Bmu = (unsigned short*)ws; ws += 4096 * sizeof(unsigned short);

  hipMemsetAsync(accum, 0, (size_t)5 * NB * sizeof(float), stream);
  returns_kernel<<<(NRET * NB + 255) / 256, 256, 0, stream>>>(inp, pert, ret);
  keys_kernel<<<(NSAMP * NSTEP + 255) / 256, 256, 0, stream>>>(keys);
  pack_kernel<<<(65536 + 4096) / 256, 256, 0, stream>>>(W_hh, w_mu, w_ls, Bhi, Blo, Bmu);
  hist_kernel<<<NB / 32, 256, 0, stream>>>(ret, W_ih, bias, Bhi, Blo, hh, cc);
  mc_kernel<<<NSAMP * (NB / 32), 256, 0, stream>>>(ret, W_ih, bias, Bhi, Blo, Bmu,
      hh, cc, b_mu, b_ls, keys, accum);
  final_kernel<<<NB / 256, 256, 0, stream>>>(accum, (float*)d_out);
}

// Round 13
// 9609.381 us; speedup vs baseline: 6.1769x; 1.0002x over previous
//
#include <hip/hip_runtime.h>
#include <stdint.h>
#include <math.h>

// ---------------------------------------------------------------------------
// Round 13: R12 structure (3 blocks/CU, 256thr/32-row mc blocks, hfh dbuf +
// hfl single, 2 barriers/step) with truncation-based hi/lo bf16 splits:
//   hi = u>>16; lo = bits(h - (h & 0xFFFF0000)) >> 16   (4 VALU vs ~10)
// Sterbenz-exact remainder; A-side split error 2^-17 -> 2^-16 (absmax
// ~1.5-3e-3 expected, threshold 9.65e-3). B-table pack keeps RNE (bits
// unchanged). Cuts ~100 VALU inst/thread-step from the dominant pipe
// (VALUBusy 46%, MfmaUtil 32% at R12).
// ---------------------------------------------------------------------------

#define HH     128
#define NG     512
#define NB     8192
#define NSAMP  100
#define NSTEP  20
#define TCAP   18
#define NHIST  126
#define NRET   127

using bfrag = __attribute__((ext_vector_type(8))) short;   // 8 bf16 = 4 VGPRs
using facc  = __attribute__((ext_vector_type(16))) float;  // 16 f32 acc

// LDS frag strides (shorts): per-(kb,hs) region 264 (8 pad), per-kb 528.
#define SHS 264
#define SKB 528
#define HFN 4224   // 8 kb * 528

// ----------------------------- threefry2x32 --------------------------------
__device__ __forceinline__ void tf2x32(uint32_t k0, uint32_t k1,
                                       uint32_t x0, uint32_t x1,
                                       uint32_t &y0, uint32_t &y1) {
  uint32_t ks2 = k0 ^ k1 ^ 0x1BD11BDAu;
  x0 += k0; x1 += k1;
#define RR(r) { x0 += x1; x1 = (x1 << (r)) | (x1 >> (32 - (r))); x1 ^= x0; }
  RR(13) RR(15) RR(26) RR(6)   x0 += k1;  x1 += ks2 + 1u;
  RR(17) RR(29) RR(16) RR(24)  x0 += ks2; x1 += k0  + 2u;
  RR(13) RR(15) RR(26) RR(6)   x0 += k0;  x1 += k1  + 3u;
  RR(17) RR(29) RR(16) RR(24)  x0 += k1;  x1 += ks2 + 4u;
  RR(13) RR(15) RR(26) RR(6)   x0 += ks2; x1 += k0  + 5u;
#undef RR
  y0 = x0; y1 = x1;
}

__device__ __forceinline__ float erfinv32(float x) {
  float w = -__logf(fmaxf(1.0f - x * x, 1e-37f));
  float p;
  if (w < 5.0f) {
    w = w - 2.5f;
    p = 2.81022636e-08f;
    p = fmaf(p, w, 3.43273939e-07f);
    p = fmaf(p, w, -3.5233877e-06f);
    p = fmaf(p, w, -4.39150654e-06f);
    p = fmaf(p, w, 0.00021858087f);
    p = fmaf(p, w, -0.00125372503f);
    p = fmaf(p, w, -0.00417768164f);
    p = fmaf(p, w, 0.246640727f);
    p = fmaf(p, w, 1.50140941f);
  } else {
    w = sqrtf(w) - 3.0f;
    p = -0.000200214257f;
    p = fmaf(p, w, 0.000100950558f);
    p = fmaf(p, w, 0.00134934322f);
    p = fmaf(p, w, -0.00367342844f);
    p = fmaf(p, w, 0.00573950773f);
    p = fmaf(p, w, -0.0076224613f);
    p = fmaf(p, w, 0.00943887047f);
    p = fmaf(p, w, 1.00167406f);
    p = fmaf(p, w, 2.83297682f);
  }
  return p * x;
}

__device__ __forceinline__ float normal32(uint32_t k0, uint32_t k1, uint32_t idx) {
  uint32_t y0, y1;
  tf2x32(k0, k1, 0u, idx, y0, y1);
  uint32_t bits = y0 ^ y1;
  float f = __uint_as_float((bits >> 9) | 0x3f800000u) - 1.0f;
  const float lo = __uint_as_float(0xBF7FFFFFu);
  float u = fmaxf(lo, f * 2.0f + lo);
  return 1.41421356f * erfinv32(u);
}

__device__ __forceinline__ float fast_sigmoid(float x) {
  return __builtin_amdgcn_rcpf(1.0f + __expf(-x));
}
__device__ __forceinline__ float fast_tanh(float x) {
  return 1.0f - 2.0f * __builtin_amdgcn_rcpf(1.0f + __expf(2.0f * x));
}

// RNE bf16 (used only for the one-time B pack — bits unchanged vs prior rounds)
__device__ __forceinline__ unsigned short f2bf(float x) {
  uint32_t u = __float_as_uint(x);
  uint32_t r = u + 0x7fffu + ((u >> 16) & 1u);
  return (unsigned short)(r >> 16);
}
__device__ __forceinline__ float bf2f(unsigned short h) {
  return __uint_as_float(((uint32_t)h) << 16);
}

// truncation split: hi = top16(h); lo = top16(h - hi) (Sterbenz-exact sub)
__device__ __forceinline__ void split_trunc(float h, unsigned short &hi,
                                            unsigned short &lo) {
  uint32_t u = __float_as_uint(h);
  hi = (unsigned short)(u >> 16);
  float hv = __uint_as_float(u & 0xFFFF0000u);
  lo = (unsigned short)(__float_as_uint(h - hv) >> 16);
}

// ------------------------------- small kernels -----------------------------
__global__ void returns_kernel(const float* __restrict__ inp,
                               const float* __restrict__ pert,
                               float* __restrict__ ret) {
  int i = blockIdx.x * blockDim.x + threadIdx.x;
  if (i >= NRET * NB) return;
  int s = i / NB, b = i - s * NB;
  float p0 = inp[s * NB + b] * (1.0f + pert[s * NB + b]);
  float p1 = inp[(s + 1) * NB + b] * (1.0f + pert[(s + 1) * NB + b]);
  ret[i] = p1 - p0;
}

__global__ void keys_kernel(uint32_t* __restrict__ keys) {
  int id = blockIdx.x * blockDim.x + threadIdx.x;
  if (id >= NSAMP * NSTEP) return;
  int s = id / NSTEP, t = id - s * NSTEP;
  uint32_t sk0, sk1, k0, k1;
  tf2x32(0u, 42u, 0u, (uint32_t)s, sk0, sk1);
  tf2x32(sk0, sk1, 0u, (uint32_t)t, k0, k1);
  keys[2 * id] = k0; keys[2 * id + 1] = k1;
}

// B-fragment pack (RNE, unchanged): Bhi/Blo[((gct*8+kb)*64+lane)*8+j]
__global__ void pack_kernel(const float* __restrict__ W_hh,
                            const float* __restrict__ w_mu,
                            const float* __restrict__ w_ls,
                            unsigned short* __restrict__ Bhi,
                            unsigned short* __restrict__ Blo,
                            unsigned short* __restrict__ Bmu) {
  int idx = blockIdx.x * blockDim.x + threadIdx.x;
  if (idx < 65536) {
    int j = idx & 7, lane = (idx >> 3) & 63, kb = (idx >> 9) & 7, gct = idx >> 12;
    int k = kb * 16 + ((lane >> 5) << 3) + j;
    int g = (gct << 5) + (lane & 31);
    float w = W_hh[k * NG + g];
    unsigned short hi = f2bf(w);
    unsigned short lo = f2bf(w - bf2f(hi));
    Bhi[idx] = hi; Blo[idx] = lo;
  } else if (idx < 65536 + 4096) {
    int i2 = idx - 65536;
    int j = i2 & 7, lane = (i2 >> 3) & 63, kb = (i2 >> 9) & 7;
    int k = kb * 16 + ((lane >> 5) << 3) + j;
    int col = lane & 31;
    float v = (col == 0) ? w_mu[k] : (col == 1 ? w_ls[k] : 0.0f);
    Bmu[i2] = f2bf(v);
  }
}

// ------------------------------ history kernel -----------------------------
__launch_bounds__(256, 1)
__global__ void hist_kernel(const float* __restrict__ ret,
                            const float* __restrict__ W_ih,
                            const float* __restrict__ bias,
                            const unsigned short* __restrict__ Bhi,
                            const unsigned short* __restrict__ Blo,
                            float* __restrict__ hout,
                            float* __restrict__ cout) {
  __shared__ unsigned short hfh[2][HFN];
  __shared__ unsigned short hfl[2][HFN];

  const int tid  = threadIdx.x;
  const int lane = tid & 63;
  const int cg   = tid >> 6;
  const int hs   = lane >> 5;
  const int m    = lane & 31;
  const int col  = (cg << 5) + m;
  const int b0   = blockIdx.x << 5;

  float wih_r[4], bb_r[4];
#pragma unroll
  for (int gi = 0; gi < 4; ++gi) {
    wih_r[gi] = W_ih[(gi << 7) + col];
    bb_r[gi]  = bias[(gi << 7) + col];
  }

  const int coff = (col >> 4) * SKB + ((col >> 3) & 1) * SHS + (col & 7);
  const int aoff = hs * SHS + m * 8;

  float c_reg[16];
#pragma unroll
  for (int reg = 0; reg < 16; ++reg) {
    int row32 = (reg & 3) + ((reg >> 2) << 3) + (hs << 2);
    c_reg[reg] = 0.0f;
    hfh[0][coff + row32 * 8] = 0;
    hfl[0][coff + row32 * 8] = 0;
  }
  __syncthreads();

  int buf = 0;
#pragma unroll 1
  for (int t = 0; t < NHIST; ++t) {
    const int nbuf = buf ^ 1;
    facc acc[4];
#pragma unroll
    for (int reg = 0; reg < 16; ++reg) {
      int row32 = (reg & 3) + ((reg >> 2) << 3) + (hs << 2);
      float xv = ret[t * NB + b0 + row32];
#pragma unroll
      for (int gi = 0; gi < 4; ++gi)
        acc[gi][reg] = fmaf(xv, wih_r[gi], bb_r[gi]);
    }
#pragma unroll 1
    for (int kb = 0; kb < 8; ++kb) {
      bfrag ah = *(const bfrag*)&hfh[buf][kb * SKB + aoff];
      bfrag al = *(const bfrag*)&hfl[buf][kb * SKB + aoff];
#pragma unroll
      for (int gp = 0; gp < 2; ++gp) {
        const int g0 = 2 * gp, g1 = 2 * gp + 1;
        const int off0 = ((((g0 << 2) + cg) << 3) + kb) * 512 + lane * 8;
        const int off1 = ((((g1 << 2) + cg) << 3) + kb) * 512 + lane * 8;
        bfrag bh0 = *(const bfrag*)&Bhi[off0];
        bfrag bl0 = *(const bfrag*)&Blo[off0];
        bfrag bh1 = *(const bfrag*)&Bhi[off1];
        bfrag bl1 = *(const bfrag*)&Blo[off1];
        acc[g0] = __builtin_amdgcn_mfma_f32_32x32x16_bf16(ah, bh0, acc[g0], 0, 0, 0);
        acc[g1] = __builtin_amdgcn_mfma_f32_32x32x16_bf16(ah, bh1, acc[g1], 0, 0, 0);
        acc[g0] = __builtin_amdgcn_mfma_f32_32x32x16_bf16(al, bh0, acc[g0], 0, 0, 0);
        acc[g1] = __builtin_amdgcn_mfma_f32_32x32x16_bf16(al, bh1, acc[g1], 0, 0, 0);
        acc[g0] = __builtin_amdgcn_mfma_f32_32x32x16_bf16(ah, bl0, acc[g0], 0, 0, 0);
        acc[g1] = __builtin_amdgcn_mfma_f32_32x32x16_bf16(ah, bl1, acc[g1], 0, 0, 0);
      }
    }
#pragma unroll
    for (int reg = 0; reg < 16; ++reg) {
      int row32 = (reg & 3) + ((reg >> 2) << 3) + (hs << 2);
      float ig = fast_sigmoid(acc[0][reg]);
      float fg = fast_sigmoid(acc[1][reg]);
      float gg = fast_tanh  (acc[2][reg]);
      float og = fast_sigmoid(acc[3][reg]);
      float c  = fmaf(fg, c_reg[reg], ig * gg);
      c_reg[reg] = c;
      float h  = og * fast_tanh(c);
      unsigned short hi, lo;
      split_trunc(h, hi, lo);
      hfh[nbuf][coff + row32 * 8] = hi;
      hfl[nbuf][coff + row32 * 8] = lo;
      if (t == NHIST - 1) {
        hout[(b0 + row32) * HH + col] = h;
        cout[(b0 + row32) * HH + col] = c;
      }
    }
    __syncthreads();
    buf = nbuf;
  }
}

// -------------------------------- MC kernel --------------------------------
__launch_bounds__(256, 3)
__global__ void mc_kernel(const float* __restrict__ ret,
                          const float* __restrict__ W_ih,
                          const float* __restrict__ bias,
                          const unsigned short* __restrict__ Bhi,
                          const unsigned short* __restrict__ Blo,
                          const unsigned short* __restrict__ Bmu,
                          const float* __restrict__ hin,
                          const float* __restrict__ cin,
                          const float* __restrict__ b_mu,
                          const float* __restrict__ b_ls,
                          const uint32_t* __restrict__ keys,
                          float* __restrict__ accum) {
  __shared__ unsigned short hfh[2][HFN];
  __shared__ unsigned short hfl[HFN];
  __shared__ float x_s[32];
  __shared__ float mu_s[32];
  __shared__ float ls_s[32];

  const int tid  = threadIdx.x;
  const int lane = tid & 63;
  const int cg   = tid >> 6;
  const int hs   = lane >> 5;
  const int m    = lane & 31;
  const int col  = (cg << 5) + m;

  const int s  = blockIdx.x >> 8;
  const int b0 = (blockIdx.x & 255) << 5;

  float wih_r[4], bb_r[4];
#pragma unroll
  for (int gi = 0; gi < 4; ++gi) {
    wih_r[gi] = W_ih[(gi << 7) + col];
    bb_r[gi]  = bias[(gi << 7) + col];
  }
  const float bmu = b_mu[0], bls = b_ls[0];

  const int coff = (col >> 4) * SKB + ((col >> 3) & 1) * SHS + (col & 7);
  const int aoff = hs * SHS + m * 8;

  // init h frags + c regs
  float c_reg[16];
#pragma unroll
  for (int reg = 0; reg < 16; ++reg) {
    int row32 = (reg & 3) + ((reg >> 2) << 3) + (hs << 2);
    int grow = b0 + row32;
    float hv = hin[grow * HH + col];
    c_reg[reg] = cin[grow * HH + col];
    unsigned short hi, lo;
    split_trunc(hv, hi, lo);
    hfh[0][coff + row32 * 8] = hi;
    hfl[coff + row32 * 8] = lo;
  }
  if (tid < 32) x_s[tid] = ret[126 * NB + b0 + tid];
  float logw = 0.0f, outv = 0.0f;
  __syncthreads();

  int buf = 0;
#pragma unroll 1
  for (int t = 0; t < NSTEP; ++t) {
    const int nbuf = buf ^ 1;

    // ---- gate matmul from h_t (hfh[buf], hfl); acc starts at 0
    facc acc[4];
#pragma unroll
    for (int gi = 0; gi < 4; ++gi)
#pragma unroll
      for (int e = 0; e < 16; ++e) acc[gi][e] = 0.0f;
#pragma unroll 1
    for (int kb = 0; kb < 8; ++kb) {
      bfrag ah = *(const bfrag*)&hfh[buf][kb * SKB + aoff];
      bfrag al = *(const bfrag*)&hfl[kb * SKB + aoff];
#pragma unroll
      for (int gp = 0; gp < 2; ++gp) {
        const int g0 = 2 * gp, g1 = 2 * gp + 1;
        const int off0 = ((((g0 << 2) + cg) << 3) + kb) * 512 + lane * 8;
        const int off1 = ((((g1 << 2) + cg) << 3) + kb) * 512 + lane * 8;
        bfrag bh0 = *(const bfrag*)&Bhi[off0];
        bfrag bl0 = *(const bfrag*)&Blo[off0];
        bfrag bh1 = *(const bfrag*)&Bhi[off1];
        bfrag bl1 = *(const bfrag*)&Blo[off1];
        acc[g0] = __builtin_amdgcn_mfma_f32_32x32x16_bf16(ah, bh0, acc[g0], 0, 0, 0);
        acc[g1] = __builtin_amdgcn_mfma_f32_32x32x16_bf16(ah, bh1, acc[g1], 0, 0, 0);
        acc[g0] = __builtin_amdgcn_mfma_f32_32x32x16_bf16(al, bh0, acc[g0], 0, 0, 0);
        acc[g1] = __builtin_amdgcn_mfma_f32_32x32x16_bf16(al, bh1, acc[g1], 0, 0, 0);
        acc[g0] = __builtin_amdgcn_mfma_f32_32x32x16_bf16(ah, bl0, acc[g0], 0, 0, 0);
        acc[g1] = __builtin_amdgcn_mfma_f32_32x32x16_bf16(ah, bl1, acc[g1], 0, 0, 0);
      }
    }
    __syncthreads();   // B1: all hfh[buf]/hfl reads done; x_s(t) visible

    // ---- epilogue: fold x*W_ih+b, activations, write hfh[nbuf] + hfl
#pragma unroll
    for (int reg = 0; reg < 16; ++reg) {
      int row32 = (reg & 3) + ((reg >> 2) << 3) + (hs << 2);
      float xv = x_s[row32];
      float ig = fast_sigmoid(acc[0][reg] + fmaf(xv, wih_r[0], bb_r[0]));
      float fg = fast_sigmoid(acc[1][reg] + fmaf(xv, wih_r[1], bb_r[1]));
      float gg = fast_tanh  (acc[2][reg] + fmaf(xv, wih_r[2], bb_r[2]));
      float og = fast_sigmoid(acc[3][reg] + fmaf(xv, wih_r[3], bb_r[3]));
      float c  = fmaf(fg, c_reg[reg], ig * gg);
      c_reg[reg] = c;
      float h  = og * fast_tanh(c);
      unsigned short hi, lo;
      split_trunc(h, hi, lo);
      hfh[nbuf][coff + row32 * 8] = hi;
      hfl[coff + row32 * 8] = lo;
    }
    __syncthreads();   // B2: h(t+1) frags visible

    if (tid < 64) {    // wave 0: mu/ls MFMA on hfh[nbuf] + RNG + x_s(t+1)
      facc am;
#pragma unroll
      for (int e = 0; e < 16; ++e) am[e] = 0.0f;
#pragma unroll 2
      for (int kb = 0; kb < 8; ++kb) {
        const bfrag bm = *(const bfrag*)&Bmu[kb * 512 + lane * 8];
        const bfrag a0 = *(const bfrag*)&hfh[nbuf][kb * SKB + aoff];
        am = __builtin_amdgcn_mfma_f32_32x32x16_bf16(a0, bm, am, 0, 0, 0);
      }
      if (m < 2) {
        float* dst = (m == 0) ? mu_s : ls_s;
#pragma unroll
        for (int reg = 0; reg < 16; ++reg)
          dst[(reg & 3) + ((reg >> 2) << 3) + (hs << 2)] = am[reg];
      }
      // same-wave LDS RAW: compiler inserts lgkmcnt wait
      float mu  = mu_s[m] + bmu;
      float lsc = fminf(fmaxf(ls_s[m] + bls, -5.0f), 2.0f);
      float sg  = __expf(lsc);
      uint32_t k0 = keys[2 * (s * NSTEP + t)];
      uint32_t k1 = keys[2 * (s * NSTEP + t) + 1];
      float z  = normal32(k0, k1, (uint32_t)(b0 + m));
      float xn = fmaf(sg, z + 0.5f, mu);
      logw -= fmaf(0.5f, z, 0.125f);
      if (t == TCAP) outv = xn;
      if (lane < 32) x_s[lane] = xn;   // visible to consumers via next B1
    }
    buf = nbuf;
  }

  if (tid < 32) {
    float wt = __expf(logw);
    float ow = outv * wt;
    int b = b0 + tid;
    atomicAdd(&accum[0 * NB + b], wt);
    atomicAdd(&accum[1 * NB + b], ow);
    atomicAdd(&accum[2 * NB + b], wt * wt);
    atomicAdd(&accum[3 * NB + b], ow * ow);
    atomicAdd(&accum[4 * NB + b], outv * wt * wt);
  }
}

// ------------------------------- final kernel ------------------------------
__global__ void final_kernel(const float* __restrict__ accum,
                             float* __restrict__ out) {
  int b = blockIdx.x * blockDim.x + threadIdx.x;
  if (b >= NB) return;
  float sw  = accum[0 * NB + b];
  float sm1 = accum[1 * NB + b];
  float sqw = accum[2 * NB + b];
  float sm2 = accum[3 * NB + b];
  float shm = accum[4 * NB + b];
  float mean = sm1 / sw;
  float sem = sm2 + sqw * mean * mean - 2.0f * shm * mean;
  sem = sqrtf(sem / (float)(NSAMP * (NSAMP - 1)));
  out[b] = mean;
  out[NB + b] = sem;
}

// ------------------------------- launcher ----------------------------------
extern "C" void kernel_launch(void* const* d_in, const int* in_sizes, int n_in,
                              void* d_out, int out_size, void* d_ws, size_t ws_size,
                              hipStream_t stream) {
  (void)in_sizes; (void)n_in; (void)out_size; (void)ws_size;
  const float* inp  = (const float*)d_in[0];
  const float* pert = (const float*)d_in[1];
  const float* W_ih = (const float*)d_in[2];
  const float* W_hh = (const float*)d_in[3];
  const float* bias = (const float*)d_in[4];
  const float* w_mu = (const float*)d_in[5];
  const float* b_mu = (const float*)d_in[6];
  const float* w_ls = (const float*)d_in[7];
  const float* b_ls = (const float*)d_in[8];

  char* ws = (char*)d_ws;
  float* ret = (float*)ws;        ws += (size_t)NRET * NB * sizeof(float);
  float* hh  = (float*)ws;        ws += (size_t)NB * HH * sizeof(float);
  float* cc  = (float*)ws;        ws += (size_t)NB * HH * sizeof(float);
  uint32_t* keys = (uint32_t*)ws; ws += (size_t)NSAMP * NSTEP * 2 * sizeof(uint32_t);
  float* accum = (float*)ws;      ws += (size_t)5 * NB * sizeof(float);
  unsigned short* Bhi = (unsigned short*)ws; ws += 65536 * sizeof(unsigned short);
  unsigned short* Blo = (unsigned short*)ws; ws += 65536 * sizeof(unsigned short);
  unsigned short* Bmu = (unsigned short*)ws; ws += 4096 * sizeof(unsigned short);

  hipMemsetAsync(accum, 0, (size_t)5 * NB * sizeof(float), stream);
  returns_kernel<<<(NRET * NB + 255) / 256, 256, 0, stream>>>(inp, pert, ret);
  keys_kernel<<<(NSAMP * NSTEP + 255) / 256, 256, 0, stream>>>(keys);
  pack_kernel<<<(65536 + 4096) / 256, 256, 0, stream>>>(W_hh, w_mu, w_ls, Bhi, Blo, Bmu);
  hist_kernel<<<NB / 32, 256, 0, stream>>>(ret, W_ih, bias, Bhi, Blo, hh, cc);
  mc_kernel<<<NSAMP * (NB / 32), 256, 0, stream>>>(ret, W_ih, bias, Bhi, Blo, Bmu,
      hh, cc, b_mu, b_ls, keys, accum);
  final_kernel<<<NB / 256, 256, 0, stream>>>(accum, (float*)d_out);
}